// Round 1
// baseline (582.241 us; speedup 1.0000x reference)
//
#include <hip/hip_runtime.h>
#include <cstddef>

#define RR 80
#define NVIEW 4
#define CH 32
#define IH 64
#define IW 64
#define NVOX (RR*RR*RR)   // 512000

// ---------------------------------------------------------------------------
// Precompute G[v][y][x][c] = sum_ic feats[v][ic][y][x] * W1[ic][c]
// (first MLP layer commutes with the bilinear blend since both are linear)
// ---------------------------------------------------------------------------
__global__ __launch_bounds__(256) void g_precompute(
    const float* __restrict__ feats, const float* __restrict__ W1,
    float* __restrict__ G)
{
    __shared__ float sW1[CH*CH];
    for (int idx = threadIdx.x; idx < CH*CH; idx += 256) sW1[idx] = W1[idx];
    __syncthreads();
    int p = blockIdx.x*256 + threadIdx.x;          // 0 .. NVIEW*IH*IW-1 (16384)
    int v  = p >> 12;                               // / (IH*IW)
    int yx = p & 4095;
    const float* fb = feats + ((size_t)v*CH)*(IH*IW) + yx;
    float g[CH];
    #pragma unroll
    for (int c=0;c<CH;++c) g[c] = 0.f;
    #pragma unroll
    for (int ic=0; ic<CH; ++ic) {
        float fv = fb[(size_t)ic*(IH*IW)];
        #pragma unroll
        for (int c=0;c<CH;++c) g[c] = fmaf(fv, sW1[ic*CH+c], g[c]);
    }
    float4* go = (float4*)(G + (size_t)p*CH);
    #pragma unroll
    for (int q=0;q<8;++q) go[q] = make_float4(g[4*q],g[4*q+1],g[4*q+2],g[4*q+3]);
}

// ---------------------------------------------------------------------------
// Main kernel: one thread per voxel. PRE=true uses the G table; PRE=false
// (fallback if ws too small) gathers raw feats and applies W1 in-register.
// ---------------------------------------------------------------------------
template<bool PRE>
__global__ __launch_bounds__(256) void dgfv_main(
    const float* __restrict__ G,      // PRE: [NVIEW][IH][IW][CH]; else feats [NVIEW][CH][IH][IW]
    const float* __restrict__ poses,  // [NVIEW][16]
    const float* __restrict__ W1, const float* __restrict__ b1,
    const float* __restrict__ W2, const float* __restrict__ b2,
    const float* __restrict__ W3, const float* __restrict__ b3,
    float* __restrict__ out)          // [16][R][R][R] laid out as c*NVOX + k*R*R + j*R + i
{
    int tid = blockIdx.x*256 + threadIdx.x;        // == k*R*R + j*R + i
    int i   = tid % RR;
    int rem = tid / RR;
    int j   = rem % RR;
    int k   = rem / RR;

    const float step = 2.0f/(float)(RR-1);
    float x = fmaf((float)i, step, -1.0f);
    float y = fmaf((float)j, step, -1.0f);
    float z = fmaf((float)k, step, -1.0f);

    float accA[8], accB[8];
    #pragma unroll
    for (int o=0;o<8;++o) { accA[o]=0.f; accB[o]=0.f; }
    float accM = 0.f;

    for (int v = 0; v < NVIEW; ++v) {
        const float* P = poses + v*16;             // uniform -> scalar loads
        float px = fmaf(P[0],x, fmaf(P[1],y, fmaf(P[2], z, P[3])));
        float py = fmaf(P[4],x, fmaf(P[5],y, fmaf(P[6], z, P[7])));
        float pz = fmaf(P[8],x, fmaf(P[9],y, fmaf(P[10],z, P[11])));
        float u  = px/pz;
        float w  = py/pz;

        float mk = (pz > 0.f && u >= 0.f && u <= (float)(IW-1)
                              && w >= 0.f && w <= (float)(IH-1)) ? 1.f : 0.f;

        float fx0 = floorf(u), fy0 = floorf(w);
        float tx = u - fx0, ty = w - fy0;
        bool bx0 = (fx0 >=  0.f) && (fx0 <= (float)(IW-1));
        bool bx1 = (fx0 >= -1.f) && (fx0 <= (float)(IW-2));
        bool by0 = (fy0 >=  0.f) && (fy0 <= (float)(IH-1));
        bool by1 = (fy0 >= -1.f) && (fy0 <= (float)(IH-2));
        int x0 = (int)fminf(fmaxf(fx0,      0.f), (float)(IW-1));
        int x1 = (int)fminf(fmaxf(fx0+1.f,  0.f), (float)(IW-1));
        int y0 = (int)fminf(fmaxf(fy0,      0.f), (float)(IH-1));
        int y1 = (int)fminf(fmaxf(fy0+1.f,  0.f), (float)(IH-1));

        float w00 = (bx0&&by0) ? (1.f-tx)*(1.f-ty) : 0.f;
        float w10 = (bx1&&by0) ? tx*(1.f-ty)       : 0.f;
        float w01 = (bx0&&by1) ? (1.f-tx)*ty       : 0.f;
        float w11 = (bx1&&by1) ? tx*ty             : 0.f;

        float h1[CH];
        if (PRE) {
            const float* gb = G + (size_t)v*(IH*IW*CH);
            const float4* p00 = (const float4*)(gb + ((size_t)(y0*IW+x0))*CH);
            const float4* p10 = (const float4*)(gb + ((size_t)(y0*IW+x1))*CH);
            const float4* p01 = (const float4*)(gb + ((size_t)(y1*IW+x0))*CH);
            const float4* p11 = (const float4*)(gb + ((size_t)(y1*IW+x1))*CH);
            #pragma unroll
            for (int q=0;q<8;++q) {
                float4 a = p00[q], b = p10[q], c = p01[q], d = p11[q];
                float r0 = fmaf(w00,a.x, fmaf(w10,b.x, fmaf(w01,c.x, w11*d.x)));
                float r1 = fmaf(w00,a.y, fmaf(w10,b.y, fmaf(w01,c.y, w11*d.y)));
                float r2 = fmaf(w00,a.z, fmaf(w10,b.z, fmaf(w01,c.z, w11*d.z)));
                float r3 = fmaf(w00,a.w, fmaf(w10,b.w, fmaf(w01,c.w, w11*d.w)));
                h1[4*q+0] = fmaxf(r0 + b1[4*q+0], 0.f);
                h1[4*q+1] = fmaxf(r1 + b1[4*q+1], 0.f);
                h1[4*q+2] = fmaxf(r2 + b1[4*q+2], 0.f);
                h1[4*q+3] = fmaxf(r3 + b1[4*q+3], 0.f);
            }
        } else {
            const float* fb = G + (size_t)v*CH*(IH*IW);  // G == feats here
            float acc[CH];
            #pragma unroll
            for (int c=0;c<CH;++c) acc[c] = 0.f;
            #pragma unroll
            for (int ic=0; ic<CH; ++ic) {
                const float* fc = fb + (size_t)ic*(IH*IW);
                float f00 = fc[y0*IW+x0];
                float f10 = fc[y0*IW+x1];
                float f01 = fc[y1*IW+x0];
                float f11 = fc[y1*IW+x1];
                float vf = fmaf(w00,f00, fmaf(w10,f10, fmaf(w01,f01, w11*f11)));
                #pragma unroll
                for (int c=0;c<CH;++c) acc[c] = fmaf(vf, W1[ic*CH+c], acc[c]);
            }
            #pragma unroll
            for (int c=0;c<CH;++c) h1[c] = fmaxf(acc[c] + b1[c], 0.f);
        }

        float h2[16];
        #pragma unroll
        for (int o=0;o<16;++o) {
            float acc = b2[o];
            #pragma unroll
            for (int ci=0; ci<CH; ++ci) acc = fmaf(h1[ci], W2[ci*16+o], acc);
            h2[o] = fmaxf(acc, 0.f);
        }

        #pragma unroll
        for (int o=0;o<8;++o) {
            float acc = b3[o];
            #pragma unroll
            for (int ci=0; ci<16; ++ci) acc = fmaf(h2[ci], W3[ci*8+o], acc);
            accA[o] = fmaf(mk, acc,     accA[o]);
            accB[o] = fmaf(mk, acc*acc, accB[o]);
        }
        accM += mk;
    }

    float S   = accM + 1e-8f;
    float inv = 1.f/S;
    float sw  = accM*inv;            // sum of weights
    #pragma unroll
    for (int o=0;o<8;++o) {
        float mean = accA[o]*inv;
        float var  = fmaf(-mean*mean, (2.f - sw), accB[o]*inv);
        out[(size_t)o*NVOX + tid]      = mean;
        out[(size_t)(8+o)*NVOX + tid]  = var;
    }
}

extern "C" void kernel_launch(void* const* d_in, const int* in_sizes, int n_in,
                              void* d_out, int out_size, void* d_ws, size_t ws_size,
                              hipStream_t stream)
{
    const float* feats = (const float*)d_in[0];
    const float* poses = (const float*)d_in[1];
    const float* W1    = (const float*)d_in[2];
    const float* b1    = (const float*)d_in[3];
    const float* W2    = (const float*)d_in[4];
    const float* b2    = (const float*)d_in[5];
    const float* W3    = (const float*)d_in[6];
    const float* b3    = (const float*)d_in[7];
    float* out = (float*)d_out;

    const size_t gbytes = (size_t)NVIEW*IH*IW*CH*sizeof(float); // 2 MB
    if (ws_size >= gbytes) {
        float* G = (float*)d_ws;
        g_precompute<<<(NVIEW*IH*IW)/256, 256, 0, stream>>>(feats, W1, G);
        dgfv_main<true><<<NVOX/256, 256, 0, stream>>>(G, poses, W1, b1, W2, b2, W3, b3, out);
    } else {
        dgfv_main<false><<<NVOX/256, 256, 0, stream>>>(feats, poses, W1, b1, W2, b2, W3, b3, out);
    }
}

// Round 2
// 562.571 us; speedup vs baseline: 1.0350x; 1.0350x over previous
//
#include <hip/hip_runtime.h>
#include <cstddef>

#define RR 80
#define NVIEW 4
#define CH 32
#define NCG (CH/4)        // 8 channel groups of 4
#define IH 64
#define IW 64
#define NPIX (IH*IW)      // 4096
#define NVOX (RR*RR*RR)   // 512000

// G layout: [v][cg][y][x][4]  (channel-group-major so gathers are lane-coalesced)
// plane stride (floats) per cg: NPIX*4 = 16384 ; per view: NCG*NPIX*4 = 131072
#define PLANE_F (NPIX*4)
#define VIEW_F  (NCG*PLANE_F)

// ---------------------------------------------------------------------------
// Precompute G[v][cg][y][x][e] = sum_ic feats[v][ic][y][x] * W1[ic][4*cg+e]
// (first MLP layer commutes with the bilinear blend since both are linear)
// ---------------------------------------------------------------------------
__global__ __launch_bounds__(256) void g_precompute(
    const float* __restrict__ feats, const float* __restrict__ W1,
    float* __restrict__ G)
{
    __shared__ float sW1[CH*CH];
    for (int idx = threadIdx.x; idx < CH*CH; idx += 256) sW1[idx] = W1[idx];
    __syncthreads();
    int p = blockIdx.x*256 + threadIdx.x;          // 0 .. NVIEW*NPIX-1 (16384)
    int v  = p >> 12;                               // / NPIX
    int yx = p & 4095;
    const float* fb = feats + ((size_t)v*CH)*NPIX + yx;
    float g[CH];
    #pragma unroll
    for (int c=0;c<CH;++c) g[c] = 0.f;
    #pragma unroll
    for (int ic=0; ic<CH; ++ic) {
        float fv = fb[(size_t)ic*NPIX];
        #pragma unroll
        for (int c=0;c<CH;++c) g[c] = fmaf(fv, sW1[ic*CH+c], g[c]);
    }
    float* gv = G + (size_t)v*VIEW_F + (size_t)yx*4;
    #pragma unroll
    for (int q=0;q<NCG;++q) {
        ((float4*)(gv + (size_t)q*PLANE_F))[0] =
            make_float4(g[4*q],g[4*q+1],g[4*q+2],g[4*q+3]);
    }
}

// ---------------------------------------------------------------------------
// Main kernel: one thread per voxel.
// ---------------------------------------------------------------------------
__global__ __launch_bounds__(256) void dgfv_main(
    const float* __restrict__ G,      // [NVIEW][NCG][IH][IW][4]
    const float* __restrict__ poses,  // [NVIEW][16]
    const float* __restrict__ b1,
    const float* __restrict__ W2, const float* __restrict__ b2,
    const float* __restrict__ W3, const float* __restrict__ b3,
    float* __restrict__ out)          // [16][R][R][R] as c*NVOX + tid
{
    int tid = blockIdx.x*256 + threadIdx.x;        // == k*R*R + j*R + i
    int i   = tid % RR;
    int rem = tid / RR;
    int j   = rem % RR;
    int k   = rem / RR;

    const float step = 2.0f/(float)(RR-1);
    float x = fmaf((float)i, step, -1.0f);
    float y = fmaf((float)j, step, -1.0f);
    float z = fmaf((float)k, step, -1.0f);

    float accA[8], accB[8];
    #pragma unroll
    for (int o=0;o<8;++o) { accA[o]=0.f; accB[o]=0.f; }
    float accM = 0.f;

    #pragma unroll
    for (int v = 0; v < NVIEW; ++v) {
        const float* P = poses + v*16;             // uniform -> scalar loads
        float px = fmaf(P[0],x, fmaf(P[1],y, fmaf(P[2], z, P[3])));
        float py = fmaf(P[4],x, fmaf(P[5],y, fmaf(P[6], z, P[7])));
        float pz = fmaf(P[8],x, fmaf(P[9],y, fmaf(P[10],z, P[11])));
        float u  = px/pz;
        float w  = py/pz;

        float mk = (pz > 0.f && u >= 0.f && u <= (float)(IW-1)
                              && w >= 0.f && w <= (float)(IH-1)) ? 1.f : 0.f;

        float fx0 = floorf(u), fy0 = floorf(w);
        float tx = u - fx0, ty = w - fy0;
        bool bx0 = (fx0 >=  0.f) && (fx0 <= (float)(IW-1));
        bool bx1 = (fx0 >= -1.f) && (fx0 <= (float)(IW-2));
        bool by0 = (fy0 >=  0.f) && (fy0 <= (float)(IH-1));
        bool by1 = (fy0 >= -1.f) && (fy0 <= (float)(IH-2));
        int x0 = (int)fminf(fmaxf(fx0,      0.f), (float)(IW-1));
        int x1 = (int)fminf(fmaxf(fx0+1.f,  0.f), (float)(IW-1));
        int y0 = (int)fminf(fmaxf(fy0,      0.f), (float)(IH-1));
        int y1 = (int)fminf(fmaxf(fy0+1.f,  0.f), (float)(IH-1));

        float w00 = (bx0&&by0) ? (1.f-tx)*(1.f-ty) : 0.f;
        float w10 = (bx1&&by0) ? tx*(1.f-ty)       : 0.f;
        float w01 = (bx0&&by1) ? (1.f-tx)*ty       : 0.f;
        float w11 = (bx1&&by1) ? tx*ty             : 0.f;

        const float* gv = G + (size_t)v*VIEW_F;
        int o00 = (y0*IW + x0)*4;
        int o10 = (y0*IW + x1)*4;
        int o01 = (y1*IW + x0)*4;
        int o11 = (y1*IW + x1)*4;

        float h1[CH];
        #pragma unroll
        for (int q=0;q<NCG;++q) {
            const float* pl = gv + q*PLANE_F;
            float4 a = *(const float4*)(pl + o00);
            float4 b = *(const float4*)(pl + o10);
            float4 c = *(const float4*)(pl + o01);
            float4 d = *(const float4*)(pl + o11);
            float r0 = fmaf(w00,a.x, fmaf(w10,b.x, fmaf(w01,c.x, w11*d.x)));
            float r1 = fmaf(w00,a.y, fmaf(w10,b.y, fmaf(w01,c.y, w11*d.y)));
            float r2 = fmaf(w00,a.z, fmaf(w10,b.z, fmaf(w01,c.z, w11*d.z)));
            float r3 = fmaf(w00,a.w, fmaf(w10,b.w, fmaf(w01,c.w, w11*d.w)));
            h1[4*q+0] = fmaxf(r0 + b1[4*q+0], 0.f);
            h1[4*q+1] = fmaxf(r1 + b1[4*q+1], 0.f);
            h1[4*q+2] = fmaxf(r2 + b1[4*q+2], 0.f);
            h1[4*q+3] = fmaxf(r3 + b1[4*q+3], 0.f);
        }

        float h2[16];
        #pragma unroll
        for (int o=0;o<16;++o) {
            float acc = b2[o];
            #pragma unroll
            for (int ci=0; ci<CH; ++ci) acc = fmaf(h1[ci], W2[ci*16+o], acc);
            h2[o] = fmaxf(acc, 0.f);
        }

        #pragma unroll
        for (int o=0;o<8;++o) {
            float acc = b3[o];
            #pragma unroll
            for (int ci=0; ci<16; ++ci) acc = fmaf(h2[ci], W3[ci*8+o], acc);
            accA[o] = fmaf(mk, acc,     accA[o]);
            accB[o] = fmaf(mk, acc*acc, accB[o]);
        }
        accM += mk;
    }

    float S   = accM + 1e-8f;
    float inv = 1.f/S;
    float sw  = accM*inv;            // sum of weights
    #pragma unroll
    for (int o=0;o<8;++o) {
        float mean = accA[o]*inv;
        float var  = fmaf(-mean*mean, (2.f - sw), accB[o]*inv);
        out[(size_t)o*NVOX + tid]      = mean;
        out[(size_t)(8+o)*NVOX + tid]  = var;
    }
}

extern "C" void kernel_launch(void* const* d_in, const int* in_sizes, int n_in,
                              void* d_out, int out_size, void* d_ws, size_t ws_size,
                              hipStream_t stream)
{
    const float* feats = (const float*)d_in[0];
    const float* poses = (const float*)d_in[1];
    const float* W1    = (const float*)d_in[2];
    const float* b1    = (const float*)d_in[3];
    const float* W2    = (const float*)d_in[4];
    const float* b2    = (const float*)d_in[5];
    const float* W3    = (const float*)d_in[6];
    const float* b3    = (const float*)d_in[7];
    float* out = (float*)d_out;

    float* G = (float*)d_ws;   // 2 MB, ws is guaranteed larger than out (32 MB)
    g_precompute<<<(NVIEW*NPIX)/256, 256, 0, stream>>>(feats, W1, G);
    dgfv_main<<<NVOX/256, 256, 0, stream>>>(G, poses, b1, W2, b2, W3, b3, out);
}

// Round 4
// 127.423 us; speedup vs baseline: 4.5693x; 4.4150x over previous
//
#include <hip/hip_runtime.h>
#include <cstddef>

#define RR 80
#define NVIEW 4
#define CH 32
#define NCG (CH/4)
#define IH 64
#define IW 64
#define NPIX (IH*IW)
#define NVOX (RR*RR*RR)   // 512000

#define PLANE_F (NPIX*4)
#define VIEW_F  (NCG*PLANE_F)

typedef _Float16 half4_t  __attribute__((ext_vector_type(4)));
typedef _Float16 half8_t  __attribute__((ext_vector_type(8)));
typedef float    float4_t __attribute__((ext_vector_type(4)));

// ---------------------------------------------------------------------------
// G[v][cg][y][x][e] = sum_ic feats[v][ic][y][x] * W1[ic][4*cg+e]
// ---------------------------------------------------------------------------
__global__ __launch_bounds__(256) void g_precompute(
    const float* __restrict__ feats, const float* __restrict__ W1,
    float* __restrict__ G)
{
    __shared__ float sW1[CH*CH];
    for (int idx = threadIdx.x; idx < CH*CH; idx += 256) sW1[idx] = W1[idx];
    __syncthreads();
    int p = blockIdx.x*256 + threadIdx.x;
    int v  = p >> 12;
    int yx = p & 4095;
    const float* fb = feats + ((size_t)v*CH)*NPIX + yx;
    float g[CH];
    #pragma unroll
    for (int c=0;c<CH;++c) g[c] = 0.f;
    #pragma unroll
    for (int ic=0; ic<CH; ++ic) {
        float fv = fb[(size_t)ic*NPIX];
        #pragma unroll
        for (int c=0;c<CH;++c) g[c] = fmaf(fv, sW1[ic*CH+c], g[c]);
    }
    float* gv = G + (size_t)v*VIEW_F + (size_t)yx*4;
    #pragma unroll
    for (int q=0;q<NCG;++q)
        ((float4*)(gv + (size_t)q*PLANE_F))[0] =
            make_float4(g[4*q],g[4*q+1],g[4*q+2],g[4*q+3]);
}

// ---------------------------------------------------------------------------
// Main: blend in fp32 vector; MLP (W2,W3) via MFMA with wave-resident weights.
// Wave = 64 voxels. Rows for MFMA = 16 (voxel,view-fixed) at a time, 4 batches.
// ---------------------------------------------------------------------------
__global__ __launch_bounds__(256) void dgfv_main(
    const float* __restrict__ G,      // [NVIEW][NCG][IH][IW][4]
    const float* __restrict__ poses,
    const float* __restrict__ b1,
    const float* __restrict__ W2, const float* __restrict__ b2,
    const float* __restrict__ W3, const float* __restrict__ b3,
    float* __restrict__ out)
{
    // per-wave LDS regions (no cross-wave sharing -> no __syncthreads needed)
    __shared__ __align__(16) _Float16 h1buf[4][64*40]; // row stride 40 f16 (80 B)
    __shared__ __align__(16) float    mkbuf[4][64];
    __shared__ __align__(16) _Float16 h2t[4][256];     // 16x16 f16 transpose buf

    const int wid  = threadIdx.x >> 6;
    const int lane = threadIdx.x & 63;
    const int lq   = lane >> 4;      // quad group 0..3
    const int lc   = lane & 15;      // col / row-in-tile 0..15
    const int voxBase = blockIdx.x*256 + wid*64;
    const int vox  = voxBase + lane;

    // ---- wave-resident weight fragments (loaded once) ----
    half8_t w2f;                     // B-frag 16x16x32: k = lq*8+j, n = lc
    #pragma unroll
    for (int j=0;j<8;++j) w2f[j] = (_Float16)W2[(lq*8+j)*16 + lc];
    half4_t w3f;                     // B-frag 16x16x16: k = lq*4+j, n = lc (<8)
    #pragma unroll
    for (int j=0;j<4;++j) w3f[j] = (lc<8) ? (_Float16)W3[(lq*4+j)*8 + lc]
                                          : (_Float16)0.f;
    const float b2c = b2[lc];
    const float b3c = (lc<8) ? b3[lc] : 0.f;
    const float4_t c1init = {b2c,b2c,b2c,b2c};
    const float4_t c2init = {b3c,b3c,b3c,b3c};

    // voxel coords
    int i   = vox % RR;
    int rem = vox / RR;
    int j_  = rem % RR;
    int k_  = rem / RR;
    const float step = 2.0f/(float)(RR-1);
    float x = fmaf((float)i,  step, -1.0f);
    float y = fmaf((float)j_, step, -1.0f);
    float z = fmaf((float)k_, step, -1.0f);

    float accA[16], accB[16], accM[16];
    #pragma unroll
    for (int q=0;q<16;++q) { accA[q]=0.f; accB[q]=0.f; accM[q]=0.f; }

    for (int v = 0; v < NVIEW; ++v) {
        const float* P = poses + v*16;
        float px = fmaf(P[0],x, fmaf(P[1],y, fmaf(P[2], z, P[3])));
        float py = fmaf(P[4],x, fmaf(P[5],y, fmaf(P[6], z, P[7])));
        float pz = fmaf(P[8],x, fmaf(P[9],y, fmaf(P[10],z, P[11])));
        float u  = px/pz;
        float w  = py/pz;

        float mk = (pz > 0.f && u >= 0.f && u <= (float)(IW-1)
                              && w >= 0.f && w <= (float)(IH-1)) ? 1.f : 0.f;

        float fx0 = floorf(u), fy0 = floorf(w);
        float tx = u - fx0, ty = w - fy0;
        bool bx0 = (fx0 >=  0.f) && (fx0 <= (float)(IW-1));
        bool bx1 = (fx0 >= -1.f) && (fx0 <= (float)(IW-2));
        bool by0 = (fy0 >=  0.f) && (fy0 <= (float)(IH-1));
        bool by1 = (fy0 >= -1.f) && (fy0 <= (float)(IH-2));
        int x0 = (int)fminf(fmaxf(fx0,      0.f), (float)(IW-1));
        int x1 = (int)fminf(fmaxf(fx0+1.f,  0.f), (float)(IW-1));
        int y0 = (int)fminf(fmaxf(fy0,      0.f), (float)(IH-1));
        int y1 = (int)fminf(fmaxf(fy0+1.f,  0.f), (float)(IH-1));

        float w00 = (bx0&&by0) ? (1.f-tx)*(1.f-ty) : 0.f;
        float w10 = (bx1&&by0) ? tx*(1.f-ty)       : 0.f;
        float w01 = (bx0&&by1) ? (1.f-tx)*ty       : 0.f;
        float w11 = (bx1&&by1) ? tx*ty             : 0.f;

        const float* gv = G + (size_t)v*VIEW_F;
        int o00 = (y0*IW + x0)*4;
        int o10 = (y0*IW + x1)*4;
        int o01 = (y1*IW + x0)*4;
        int o11 = (y1*IW + x1)*4;

        // blend -> h1 (f16) -> LDS row `lane`
        _Float16* rowp = &h1buf[wid][lane*40];
        #pragma unroll
        for (int q=0;q<NCG;++q) {
            const float* pl = gv + q*PLANE_F;
            float4 a = *(const float4*)(pl + o00);
            float4 b = *(const float4*)(pl + o10);
            float4 c = *(const float4*)(pl + o01);
            float4 d = *(const float4*)(pl + o11);
            float r0 = fmaf(w00,a.x, fmaf(w10,b.x, fmaf(w01,c.x, w11*d.x))) + b1[4*q+0];
            float r1 = fmaf(w00,a.y, fmaf(w10,b.y, fmaf(w01,c.y, w11*d.y))) + b1[4*q+1];
            float r2 = fmaf(w00,a.z, fmaf(w10,b.z, fmaf(w01,c.z, w11*d.z))) + b1[4*q+2];
            float r3 = fmaf(w00,a.w, fmaf(w10,b.w, fmaf(w01,c.w, w11*d.w))) + b1[4*q+3];
            half4_t hq;
            hq[0] = (_Float16)fmaxf(r0,0.f);
            hq[1] = (_Float16)fmaxf(r1,0.f);
            hq[2] = (_Float16)fmaxf(r2,0.f);
            hq[3] = (_Float16)fmaxf(r3,0.f);
            ((half4_t*)rowp)[q] = hq;          // ds_write_b64
        }
        mkbuf[wid][lane] = mk;
        __builtin_amdgcn_wave_barrier();

        // 4 batches of 16 rows (voxels voxBase+16b .. +15), MFMA MLP
        #pragma unroll
        for (int b=0;b<4;++b) {
            half8_t a1 = *(const half8_t*)&h1buf[wid][(16*b+lc)*40 + lq*8]; // ds_read_b128
            float4_t d1 = __builtin_amdgcn_mfma_f32_16x16x32_f16(a1, w2f, c1init, 0,0,0);
            #pragma unroll
            for (int r=0;r<4;++r)
                h2t[wid][(4*lq+r)*16 + lc] = (_Float16)fmaxf(d1[r], 0.f);
            __builtin_amdgcn_wave_barrier();
            half4_t a2 = *(const half4_t*)&h2t[wid][lc*16 + lq*4];          // ds_read_b64
            float4_t d2 = __builtin_amdgcn_mfma_f32_16x16x16f16(a2, w3f, c2init, 0,0,0);
            float4 mkv = *(const float4*)&mkbuf[wid][16*b + lq*4];
            #pragma unroll
            for (int r=0;r<4;++r) {
                float h3 = d2[r];
                float m  = (r==0)?mkv.x:(r==1)?mkv.y:(r==2)?mkv.z:mkv.w;
                int idx = 4*b + r;
                accA[idx] = fmaf(m, h3,    accA[idx]);
                accB[idx] = fmaf(m, h3*h3, accB[idx]);
                accM[idx] += m;
            }
            __builtin_amdgcn_wave_barrier();
        }
        __builtin_amdgcn_wave_barrier();
    }

    // finalize: mean/var in distributed layout -> LDS transpose -> coalesced store
    float* fb = (float*)&h1buf[wid][0];   // 64 rows x 17 f32 (4352 B < 5120 B)
    if (lc < 8) {
        #pragma unroll
        for (int b=0;b<4;++b) {
            #pragma unroll
            for (int r=0;r<4;++r) {
                int idx  = 4*b + r;
                int voxr = 16*b + 4*lq + r;
                float S   = accM[idx] + 1e-8f;
                float inv = 1.f/S;
                float sw  = accM[idx]*inv;
                float mean= accA[idx]*inv;
                float var = fmaf(-mean*mean, (2.f - sw), accB[idx]*inv);
                fb[voxr*17 + lc]     = mean;
                fb[voxr*17 + 8 + lc] = var;
            }
        }
    }
    __builtin_amdgcn_wave_barrier();
    #pragma unroll
    for (int c=0;c<16;++c)
        out[(size_t)c*NVOX + vox] = fb[lane*17 + c];
}

extern "C" void kernel_launch(void* const* d_in, const int* in_sizes, int n_in,
                              void* d_out, int out_size, void* d_ws, size_t ws_size,
                              hipStream_t stream)
{
    const float* feats = (const float*)d_in[0];
    const float* poses = (const float*)d_in[1];
    const float* W1    = (const float*)d_in[2];
    const float* b1    = (const float*)d_in[3];
    const float* W2    = (const float*)d_in[4];
    const float* b2    = (const float*)d_in[5];
    const float* W3    = (const float*)d_in[6];
    const float* b3    = (const float*)d_in[7];
    float* out = (float*)d_out;

    float* G = (float*)d_ws;   // 2 MB
    g_precompute<<<(NVIEW*NPIX)/256, 256, 0, stream>>>(feats, W1, G);
    dgfv_main<<<NVOX/256, 256, 0, stream>>>(G, poses, b1, W2, b2, W3, b3, out);
}

// Round 5
// 113.658 us; speedup vs baseline: 5.1228x; 1.1211x over previous
//
#include <hip/hip_runtime.h>
#include <cstddef>

#define RR 80
#define NVIEW 4
#define CH 32
#define IH 64
#define IW 64
#define NPIX (IH*IW)
#define NVOX (RR*RR*RR)   // 512000

// G (f16) layout: [v][grp(4 x 8ch)][y][x][8 f16 = 16B]
#define PLANE_H (NPIX*8)          // 32768 f16 per 8-ch plane
#define VIEW_H  (4*PLANE_H)

typedef _Float16 half2_t  __attribute__((ext_vector_type(2)));
typedef _Float16 half4_t  __attribute__((ext_vector_type(4)));
typedef _Float16 half8_t  __attribute__((ext_vector_type(8)));
typedef float    float4_t __attribute__((ext_vector_type(4)));

// ---------------------------------------------------------------------------
// G[v][g][y][x][e] = sum_ic feats[v][ic][y][x] * W1[ic][8*g+e]  (f16 output)
// thread = (pixel, half): computes 16 channels -> 2 half8 stores. 128 blocks.
// ---------------------------------------------------------------------------
__global__ __launch_bounds__(256) void g_precompute(
    const float* __restrict__ feats, const float* __restrict__ W1,
    _Float16* __restrict__ G)
{
    __shared__ float sW1[CH*CH];
    for (int idx = threadIdx.x; idx < CH*CH; idx += 256) sW1[idx] = W1[idx];
    __syncthreads();
    int t  = blockIdx.x*256 + threadIdx.x;   // 0 .. 32767
    int p  = t >> 1;                          // pixel 0..16383
    int hf = t & 1;                           // channel half
    int v  = p >> 12;
    int yx = p & 4095;
    const float* fb = feats + ((size_t)v*CH)*NPIX + yx;
    float g[16];
    #pragma unroll
    for (int c=0;c<16;++c) g[c] = 0.f;
    #pragma unroll
    for (int ic=0; ic<CH; ++ic) {
        float fv = fb[(size_t)ic*NPIX];
        #pragma unroll
        for (int c=0;c<16;++c) g[c] = fmaf(fv, sW1[ic*CH + 16*hf + c], g[c]);
    }
    _Float16* gv = G + (size_t)v*VIEW_H + (size_t)yx*8;
    #pragma unroll
    for (int gg=0; gg<2; ++gg) {
        half8_t h;
        #pragma unroll
        for (int e=0;e<8;++e) h[e] = (_Float16)g[8*gg+e];
        *(half8_t*)(gv + (size_t)(2*hf+gg)*PLANE_H) = h;
    }
}

// ---------------------------------------------------------------------------
// Main: f16 packed blend; MLP (W2,W3) via MFMA with wave-resident weights.
// ---------------------------------------------------------------------------
__global__ __launch_bounds__(256) void dgfv_main(
    const _Float16* __restrict__ G,   // [NVIEW][4][IH][IW][8]
    const float* __restrict__ poses,
    const float* __restrict__ b1,
    const float* __restrict__ W2, const float* __restrict__ b2,
    const float* __restrict__ W3, const float* __restrict__ b3,
    float* __restrict__ out)
{
    // per-wave LDS regions (single-wave producer/consumer -> wave_barrier only)
    __shared__ __align__(16) _Float16 h1buf[4][64*40]; // row stride 40 f16 (80 B)
    __shared__ __align__(16) float    mkbuf[4][64];
    __shared__ __align__(16) _Float16 h2t[4][256];     // 16x16 f16 transpose buf

    const int wid  = threadIdx.x >> 6;
    const int lane = threadIdx.x & 63;
    const int lq   = lane >> 4;
    const int lc   = lane & 15;
    const int voxBase = blockIdx.x*256 + wid*64;
    const int vox  = voxBase + lane;

    // wave-resident weight fragments
    half8_t w2f;                     // B-frag 16x16x32: k = lq*8+j, n = lc
    #pragma unroll
    for (int j=0;j<8;++j) w2f[j] = (_Float16)W2[(lq*8+j)*16 + lc];
    half4_t w3f;                     // B-frag 16x16x16: k = lq*4+j, n = lc (<8)
    #pragma unroll
    for (int j=0;j<4;++j) w3f[j] = (lc<8) ? (_Float16)W3[(lq*4+j)*8 + lc]
                                          : (_Float16)0.f;
    const float b2c = b2[lc];
    const float b3c = (lc<8) ? b3[lc] : 0.f;
    const float4_t c1init = {b2c,b2c,b2c,b2c};
    const float4_t c2init = {b3c,b3c,b3c,b3c};

    half8_t b1h[4];                  // bias as f16, per 8-ch group
    #pragma unroll
    for (int g=0;g<4;++g) {
        #pragma unroll
        for (int e=0;e<8;++e) b1h[g][e] = (_Float16)b1[8*g+e];
    }

    // voxel coords
    int i   = vox % RR;
    int rem = vox / RR;
    int j_  = rem % RR;
    int k_  = rem / RR;
    const float step = 2.0f/(float)(RR-1);
    float x = fmaf((float)i,  step, -1.0f);
    float y = fmaf((float)j_, step, -1.0f);
    float z = fmaf((float)k_, step, -1.0f);

    float accA[16], accB[16], accM[16];
    #pragma unroll
    for (int q=0;q<16;++q) { accA[q]=0.f; accB[q]=0.f; accM[q]=0.f; }

    for (int v = 0; v < NVIEW; ++v) {
        const float* P = poses + v*16;
        float px = fmaf(P[0],x, fmaf(P[1],y, fmaf(P[2], z, P[3])));
        float py = fmaf(P[4],x, fmaf(P[5],y, fmaf(P[6], z, P[7])));
        float pz = fmaf(P[8],x, fmaf(P[9],y, fmaf(P[10],z, P[11])));
        float u  = px/pz;
        float w  = py/pz;

        float mk = (pz > 0.f && u >= 0.f && u <= (float)(IW-1)
                              && w >= 0.f && w <= (float)(IH-1)) ? 1.f : 0.f;

        float fx0 = floorf(u), fy0 = floorf(w);
        float tx = u - fx0, ty = w - fy0;
        bool bx0 = (fx0 >=  0.f) && (fx0 <= (float)(IW-1));
        bool bx1 = (fx0 >= -1.f) && (fx0 <= (float)(IW-2));
        bool by0 = (fy0 >=  0.f) && (fy0 <= (float)(IH-1));
        bool by1 = (fy0 >= -1.f) && (fy0 <= (float)(IH-2));
        int x0 = (int)fminf(fmaxf(fx0,      0.f), (float)(IW-1));
        int x1 = (int)fminf(fmaxf(fx0+1.f,  0.f), (float)(IW-1));
        int y0 = (int)fminf(fmaxf(fy0,      0.f), (float)(IH-1));
        int y1 = (int)fminf(fmaxf(fy0+1.f,  0.f), (float)(IH-1));

        float w00 = (bx0&&by0) ? (1.f-tx)*(1.f-ty) : 0.f;
        float w10 = (bx1&&by0) ? tx*(1.f-ty)       : 0.f;
        float w01 = (bx0&&by1) ? (1.f-tx)*ty       : 0.f;
        float w11 = (bx1&&by1) ? tx*ty             : 0.f;

        _Float16 w00h = (_Float16)w00, w10h = (_Float16)w10;
        _Float16 w01h = (_Float16)w01, w11h = (_Float16)w11;

        const _Float16* gv = G + (size_t)v*VIEW_H;
        int o00 = (y0*IW + x0)*8;
        int o10 = (y0*IW + x1)*8;
        int o01 = (y1*IW + x0)*8;
        int o11 = (y1*IW + x1)*8;

        // packed f16 blend -> h1 row (4 x b128 writes)
        _Float16* rowp = &h1buf[wid][lane*40];
        #pragma unroll
        for (int g=0;g<4;++g) {
            const _Float16* pl = gv + (size_t)g*PLANE_H;
            half8_t a = *(const half8_t*)(pl + o00);
            half8_t b = *(const half8_t*)(pl + o10);
            half8_t c = *(const half8_t*)(pl + o01);
            half8_t d = *(const half8_t*)(pl + o11);
            half8_t r = a*w00h + b*w10h + c*w01h + d*w11h + b1h[g];
            r = __builtin_elementwise_max(r, (half8_t)(_Float16)0.f);
            ((half8_t*)rowp)[g] = r;
        }
        mkbuf[wid][lane] = mk;
        __builtin_amdgcn_wave_barrier();

        // 4 batches of 16 voxel-rows through the 2-layer MFMA MLP
        #pragma unroll
        for (int b=0;b<4;++b) {
            half8_t a1 = *(const half8_t*)&h1buf[wid][(16*b+lc)*40 + lq*8];
            float4_t d1 = __builtin_amdgcn_mfma_f32_16x16x32_f16(a1, w2f, c1init, 0,0,0);
            #pragma unroll
            for (int r=0;r<4;++r)
                h2t[wid][(4*lq+r)*16 + lc] = (_Float16)fmaxf(d1[r], 0.f);
            __builtin_amdgcn_wave_barrier();
            half4_t a2 = *(const half4_t*)&h2t[wid][lc*16 + lq*4];
            float4_t d2 = __builtin_amdgcn_mfma_f32_16x16x16f16(a2, w3f, c2init, 0,0,0);
            float4 mkv = *(const float4*)&mkbuf[wid][16*b + lq*4];
            #pragma unroll
            for (int r=0;r<4;++r) {
                float h3 = d2[r];
                float m  = (r==0)?mkv.x:(r==1)?mkv.y:(r==2)?mkv.z:mkv.w;
                int idx = 4*b + r;
                accA[idx] = fmaf(m, h3,    accA[idx]);
                accB[idx] = fmaf(m, h3*h3, accB[idx]);
                accM[idx] += m;
            }
            __builtin_amdgcn_wave_barrier();
        }
        __builtin_amdgcn_wave_barrier();
    }

    // finalize: mean/var -> LDS transpose -> coalesced store
    float* fb = (float*)&h1buf[wid][0];   // 64 rows x 17 f32
    if (lc < 8) {
        #pragma unroll
        for (int b=0;b<4;++b) {
            #pragma unroll
            for (int r=0;r<4;++r) {
                int idx  = 4*b + r;
                int voxr = 16*b + 4*lq + r;
                float S   = accM[idx] + 1e-8f;
                float inv = 1.f/S;
                float sw  = accM[idx]*inv;
                float mean= accA[idx]*inv;
                float var = fmaf(-mean*mean, (2.f - sw), accB[idx]*inv);
                fb[voxr*17 + lc]     = mean;
                fb[voxr*17 + 8 + lc] = var;
            }
        }
    }
    __builtin_amdgcn_wave_barrier();
    #pragma unroll
    for (int c=0;c<16;++c)
        out[(size_t)c*NVOX + vox] = fb[lane*17 + c];
}

extern "C" void kernel_launch(void* const* d_in, const int* in_sizes, int n_in,
                              void* d_out, int out_size, void* d_ws, size_t ws_size,
                              hipStream_t stream)
{
    const float* feats = (const float*)d_in[0];
    const float* poses = (const float*)d_in[1];
    const float* W1    = (const float*)d_in[2];
    const float* b1    = (const float*)d_in[3];
    const float* W2    = (const float*)d_in[4];
    const float* b2    = (const float*)d_in[5];
    const float* W3    = (const float*)d_in[6];
    const float* b3    = (const float*)d_in[7];
    float* out = (float*)d_out;

    _Float16* G = (_Float16*)d_ws;   // 1 MB
    g_precompute<<<(NVIEW*NPIX*2)/256, 256, 0, stream>>>(feats, W1, G);
    dgfv_main<<<NVOX/256, 256, 0, stream>>>(G, poses, b1, W2, b2, W3, b3, out);
}

// Round 6
// 110.476 us; speedup vs baseline: 5.2703x; 1.0288x over previous
//
#include <hip/hip_runtime.h>
#include <cstddef>

#define RR 80
#define NVIEW 4
#define CH 32
#define IH 64
#define IW 64
#define NPIX (IH*IW)
#define NVOX (RR*RR*RR)   // 512000

// G (f16) layout: [v][grp(4 x 8ch)][y][x][8 f16 = 16B]
#define PLANE_H (NPIX*8)          // 32768 f16 per 8-ch plane
#define VIEW_H  (4*PLANE_H)

typedef _Float16 half4_t  __attribute__((ext_vector_type(4)));
typedef _Float16 half8_t  __attribute__((ext_vector_type(8)));
typedef float    float4_t __attribute__((ext_vector_type(4)));

#define H2T_STRIDE 20   // f16; write banks form a full 32-bank permutation

// ---------------------------------------------------------------------------
// G[v][g][y][x][e] = sum_ic feats[v][ic][y][x] * W1[ic][8*g+e]  (f16 output)
// 256 blocks; channel-group g is block-uniform so global loads stay coalesced.
// ---------------------------------------------------------------------------
__global__ __launch_bounds__(256) void g_precompute(
    const float* __restrict__ feats, const float* __restrict__ W1,
    _Float16* __restrict__ G)
{
    int g = blockIdx.x >> 6;                        // 0..3 (8-ch group)
    int p = (blockIdx.x & 63)*256 + threadIdx.x;    // pixel 0..16383
    __shared__ float sW1[CH*8];
    if (threadIdx.x < CH*8) {
        int ic = threadIdx.x >> 3, e = threadIdx.x & 7;
        sW1[threadIdx.x] = W1[ic*CH + 8*g + e];
    }
    __syncthreads();
    int v  = p >> 12;
    int yx = p & 4095;
    const float* fb = feats + ((size_t)v*CH)*NPIX + yx;
    float acc[8];
    #pragma unroll
    for (int e=0;e<8;++e) acc[e] = 0.f;
    #pragma unroll
    for (int ic=0; ic<CH; ++ic) {
        float fv = fb[(size_t)ic*NPIX];
        #pragma unroll
        for (int e=0;e<8;++e) acc[e] = fmaf(fv, sW1[ic*8+e], acc[e]);
    }
    half8_t h;
    #pragma unroll
    for (int e=0;e<8;++e) h[e] = (_Float16)acc[e];
    *(half8_t*)(G + (size_t)v*VIEW_H + (size_t)g*PLANE_H + (size_t)yx*8) = h;
}

// ---------------------------------------------------------------------------
// Main: f16 packed blend; MLP (W2,W3) via MFMA with wave-resident weights.
// ---------------------------------------------------------------------------
__global__ __launch_bounds__(256) void dgfv_main(
    const _Float16* __restrict__ G,   // [NVIEW][4][IH][IW][8]
    const float* __restrict__ poses,
    const float* __restrict__ b1,
    const float* __restrict__ W2, const float* __restrict__ b2,
    const float* __restrict__ W3, const float* __restrict__ b3,
    float* __restrict__ out)
{
    // per-wave LDS regions (single-wave producer/consumer -> wave_barrier only)
    __shared__ __align__(16) _Float16 h1buf[4][64*40];        // 80 B row stride
    __shared__ __align__(16) float    mkbuf[4][64];
    __shared__ __align__(16) _Float16 h2t[4][16*H2T_STRIDE];  // padded 16x16

    const int wid  = threadIdx.x >> 6;
    const int lane = threadIdx.x & 63;
    const int lq   = lane >> 4;
    const int lc   = lane & 15;
    const int voxBase = blockIdx.x*256 + wid*64;
    const int vox  = voxBase + lane;

    // wave-resident weight fragments
    half8_t w2f;                     // B-frag 16x16x32: k = lq*8+j, n = lc
    #pragma unroll
    for (int j=0;j<8;++j) w2f[j] = (_Float16)W2[(lq*8+j)*16 + lc];
    half4_t w3f;                     // B-frag 16x16x16: k = lq*4+j, n = lc (<8)
    #pragma unroll
    for (int j=0;j<4;++j) w3f[j] = (lc<8) ? (_Float16)W3[(lq*4+j)*8 + lc]
                                          : (_Float16)0.f;
    const float b2c = b2[lc];
    const float b3c = (lc<8) ? b3[lc] : 0.f;
    const float4_t c1init = {b2c,b2c,b2c,b2c};
    const float4_t c2init = {b3c,b3c,b3c,b3c};

    half8_t b1h[4];
    #pragma unroll
    for (int g=0;g<4;++g) {
        #pragma unroll
        for (int e=0;e<8;++e) b1h[g][e] = (_Float16)b1[8*g+e];
    }

    // voxel coords
    int i   = vox % RR;
    int rem = vox / RR;
    int j_  = rem % RR;
    int k_  = rem / RR;
    const float step = 2.0f/(float)(RR-1);
    float x = fmaf((float)i,  step, -1.0f);
    float y = fmaf((float)j_, step, -1.0f);
    float z = fmaf((float)k_, step, -1.0f);

    float accA[16], accB[16], accM[16];
    #pragma unroll
    for (int q=0;q<16;++q) { accA[q]=0.f; accB[q]=0.f; accM[q]=0.f; }

    for (int v = 0; v < NVIEW; ++v) {
        const float* P = poses + v*16;
        float px = fmaf(P[0],x, fmaf(P[1],y, fmaf(P[2], z, P[3])));
        float py = fmaf(P[4],x, fmaf(P[5],y, fmaf(P[6], z, P[7])));
        float pz = fmaf(P[8],x, fmaf(P[9],y, fmaf(P[10],z, P[11])));
        float u  = px/pz;
        float w  = py/pz;

        float mk = (pz > 0.f && u >= 0.f && u <= (float)(IW-1)
                              && w >= 0.f && w <= (float)(IH-1)) ? 1.f : 0.f;

        float fx0 = floorf(u), fy0 = floorf(w);
        float tx = u - fx0, ty = w - fy0;
        bool bx0 = (fx0 >=  0.f) && (fx0 <= (float)(IW-1));
        bool bx1 = (fx0 >= -1.f) && (fx0 <= (float)(IW-2));
        bool by0 = (fy0 >=  0.f) && (fy0 <= (float)(IH-1));
        bool by1 = (fy0 >= -1.f) && (fy0 <= (float)(IH-2));
        int x0 = (int)fminf(fmaxf(fx0,      0.f), (float)(IW-1));
        int x1 = (int)fminf(fmaxf(fx0+1.f,  0.f), (float)(IW-1));
        int y0 = (int)fminf(fmaxf(fy0,      0.f), (float)(IH-1));
        int y1 = (int)fminf(fmaxf(fy0+1.f,  0.f), (float)(IH-1));

        float w00 = (bx0&&by0) ? (1.f-tx)*(1.f-ty) : 0.f;
        float w10 = (bx1&&by0) ? tx*(1.f-ty)       : 0.f;
        float w01 = (bx0&&by1) ? (1.f-tx)*ty       : 0.f;
        float w11 = (bx1&&by1) ? tx*ty             : 0.f;

        _Float16 w00h = (_Float16)w00, w10h = (_Float16)w10;
        _Float16 w01h = (_Float16)w01, w11h = (_Float16)w11;

        const _Float16* gv = G + (size_t)v*VIEW_H;
        int o00 = (y0*IW + x0)*8;
        int o10 = (y0*IW + x1)*8;
        int o01 = (y1*IW + x0)*8;
        int o11 = (y1*IW + x1)*8;

        // packed f16 blend -> h1 row (4 x b128 writes)
        _Float16* rowp = &h1buf[wid][lane*40];
        #pragma unroll
        for (int g=0;g<4;++g) {
            const _Float16* pl = gv + (size_t)g*PLANE_H;
            half8_t a = *(const half8_t*)(pl + o00);
            half8_t b = *(const half8_t*)(pl + o10);
            half8_t c = *(const half8_t*)(pl + o01);
            half8_t d = *(const half8_t*)(pl + o11);
            half8_t r = a*w00h + b*w10h + c*w01h + d*w11h + b1h[g];
            r = __builtin_elementwise_max(r, (half8_t)(_Float16)0.f);
            ((half8_t*)rowp)[g] = r;
        }
        mkbuf[wid][lane] = mk;
        __builtin_amdgcn_wave_barrier();

        // 4 batches of 16 voxel-rows through the 2-layer MFMA MLP
        #pragma unroll
        for (int b=0;b<4;++b) {
            half8_t a1 = *(const half8_t*)&h1buf[wid][(16*b+lc)*40 + lq*8];
            float4_t d1 = __builtin_amdgcn_mfma_f32_16x16x32_f16(a1, w2f, c1init, 0,0,0);
            #pragma unroll
            for (int r=0;r<4;++r)
                h2t[wid][(4*lq+r)*H2T_STRIDE + lc] = (_Float16)fmaxf(d1[r], 0.f);
            __builtin_amdgcn_wave_barrier();
            half4_t a2 = *(const half4_t*)&h2t[wid][lc*H2T_STRIDE + lq*4];
            float4_t d2 = __builtin_amdgcn_mfma_f32_16x16x16f16(a2, w3f, c2init, 0,0,0);
            float4 mkv = *(const float4*)&mkbuf[wid][16*b + lq*4];
            #pragma unroll
            for (int r=0;r<4;++r) {
                float h3 = d2[r];
                float m  = (r==0)?mkv.x:(r==1)?mkv.y:(r==2)?mkv.z:mkv.w;
                int idx = 4*b + r;
                accA[idx] = fmaf(m, h3,    accA[idx]);
                accB[idx] = fmaf(m, h3*h3, accB[idx]);
                accM[idx] += m;
            }
            __builtin_amdgcn_wave_barrier();
        }
        __builtin_amdgcn_wave_barrier();
    }

    // finalize: mean/var -> LDS transpose -> coalesced store
    float* fb = (float*)&h1buf[wid][0];   // 64 rows x 17 f32
    if (lc < 8) {
        #pragma unroll
        for (int b=0;b<4;++b) {
            #pragma unroll
            for (int r=0;r<4;++r) {
                int idx  = 4*b + r;
                int voxr = 16*b + 4*lq + r;
                float S   = accM[idx] + 1e-8f;
                float inv = 1.f/S;
                float sw  = accM[idx]*inv;
                float mean= accA[idx]*inv;
                float var = fmaf(-mean*mean, (2.f - sw), accB[idx]*inv);
                fb[voxr*17 + lc]     = mean;
                fb[voxr*17 + 8 + lc] = var;
            }
        }
    }
    __builtin_amdgcn_wave_barrier();
    #pragma unroll
    for (int c=0;c<16;++c)
        out[(size_t)c*NVOX + vox] = fb[lane*17 + c];
}

extern "C" void kernel_launch(void* const* d_in, const int* in_sizes, int n_in,
                              void* d_out, int out_size, void* d_ws, size_t ws_size,
                              hipStream_t stream)
{
    const float* feats = (const float*)d_in[0];
    const float* poses = (const float*)d_in[1];
    const float* W1    = (const float*)d_in[2];
    const float* b1    = (const float*)d_in[3];
    const float* W2    = (const float*)d_in[4];
    const float* b2    = (const float*)d_in[5];
    const float* W3    = (const float*)d_in[6];
    const float* b3    = (const float*)d_in[7];
    float* out = (float*)d_out;

    _Float16* G = (_Float16*)d_ws;   // 1 MB
    g_precompute<<<256, 256, 0, stream>>>(feats, W1, G);
    dgfv_main<<<NVOX/256, 256, 0, stream>>>(G, poses, b1, W2, b2, W3, b3, out);
}